// Round 1
// baseline (364.131 us; speedup 1.0000x reference)
//
#include <hip/hip_runtime.h>
#include <cstdint>
#include <cstddef>

// ---------------------------------------------------------------------------
// SelectiveScan2D (Mamba-style block), MI355X/gfx950.
// Pipeline:
//   1. cast_misc:       x (f32) -> x_h (f16);  A_log -> negA = -exp(A_log) (f32)
//   2. transpose_cast:  W_in, W_dt, W_out (f32, K x N) -> f16 (N x K) for gemm_bt
//   3. gemm_bt<f16out>: xz = x @ W_in + b_in           (4096 x 4096, f16)
//   4. conv_silu:       x_in = silu(causal depthwise conv(xz[:, :2048]))  (f16)
//   5. gemm_bt<f16out>: dtraw = x_in @ W_dt + b_dt     (4096 x 2048, f16)
//   6. scan_kernel:     y = x_in*(sum_n exp(softplus(dtraw)*negA_n) + D)*silu(z)
//   7. gemm_bt<f32out>: out = y @ W_out + b_out        (4096 x 1024, f32)
// GEMMs: m97 structure — 128x128 tile, 4 waves, BK=32, global_load_lds(16B),
// v_mfma_f32_16x16x32_f16, fp32 accumulate. fp16 inputs keep absmax ~5e-5
// (threshold 8.8e-4).
// ---------------------------------------------------------------------------

typedef _Float16 half8 __attribute__((ext_vector_type(8)));
typedef float floatx4 __attribute__((ext_vector_type(4)));

typedef const char __attribute__((address_space(1)))* gbl_cptr;
typedef char __attribute__((address_space(3)))* lds_ptr;

__device__ __forceinline__ void async_copy16(const void* g, void* l) {
  __builtin_amdgcn_global_load_lds((gbl_cptr)g, (lds_ptr)l, 16, 0, 0);
}

// ---- GEMM: C[M,N] = A[M,K] @ Bt[N,K]^T + bias;  M,N mult of 128, K mult of 32
template <bool HALF_OUT>
__global__ __launch_bounds__(256) void gemm_bt(
    const _Float16* __restrict__ A, const _Float16* __restrict__ Bt,
    const float* __restrict__ bias, float* __restrict__ Cf,
    _Float16* __restrict__ Ch, int N, int K) {
  __shared__ _Float16 lA[128 * 32];
  __shared__ _Float16 lB[128 * 32];
  const int tid = threadIdx.x;
  const int rowBase = blockIdx.y * 128;
  const int colBase = blockIdx.x * 128;
  const int lane = tid & 63;
  const int wv = tid >> 6;
  const int wr = (wv >> 1) * 64;  // wave row offset in tile
  const int wc = (wv & 1) * 64;   // wave col offset in tile
  const int lr = lane & 15;
  const int lq = lane >> 4;

  floatx4 acc[4][4];
#pragma unroll
  for (int i = 0; i < 4; ++i)
#pragma unroll
    for (int j = 0; j < 4; ++j) acc[i][j] = (floatx4)0.0f;

  // staging map: thread -> 16B granule. 128x32 f16 tile = 8KB = 512 granules.
  const int ra = tid >> 2;        // row 0..63 (and +64 on second call)
  const int ch = (tid & 3) * 8;   // f16 offset of 16B chunk within row
  const _Float16* gA = A + (size_t)(rowBase + ra) * K + ch;
  const _Float16* gB = Bt + (size_t)(colBase + ra) * K + ch;

  for (int k0 = 0; k0 < K; k0 += 32) {
    async_copy16(gA + k0, &lA[ra * 32 + ch]);
    async_copy16(gA + (size_t)64 * K + k0, &lA[(ra + 64) * 32 + ch]);
    async_copy16(gB + k0, &lB[ra * 32 + ch]);
    async_copy16(gB + (size_t)64 * K + k0, &lB[(ra + 64) * 32 + ch]);
    __syncthreads();  // drains vmcnt before barrier

    half8 af[4], bf[4];
#pragma unroll
    for (int i = 0; i < 4; ++i)
      af[i] = *(const half8*)&lA[(wr + i * 16 + lr) * 32 + lq * 8];
#pragma unroll
    for (int j = 0; j < 4; ++j)
      bf[j] = *(const half8*)&lB[(wc + j * 16 + lr) * 32 + lq * 8];
#pragma unroll
    for (int i = 0; i < 4; ++i)
#pragma unroll
      for (int j = 0; j < 4; ++j)
        acc[i][j] = __builtin_amdgcn_mfma_f32_16x16x32_f16(af[i], bf[j],
                                                           acc[i][j], 0, 0, 0);
    __syncthreads();
  }

  // C/D layout: col = lane&15, row = (lane>>4)*4 + reg  (guide §3, m89-verified)
#pragma unroll
  for (int j = 0; j < 4; ++j) {
    const int col = colBase + wc + j * 16 + lr;
    const float bv = bias[col];
#pragma unroll
    for (int i = 0; i < 4; ++i) {
      const int row0 = rowBase + wr + i * 16 + lq * 4;
#pragma unroll
      for (int r = 0; r < 4; ++r) {
        const float v = acc[i][j][r] + bv;
        if (HALF_OUT)
          Ch[(size_t)(row0 + r) * N + col] = (_Float16)v;
        else
          Cf[(size_t)(row0 + r) * N + col] = v;
      }
    }
  }
}

// ---- x -> f16 cast + negA = -exp(A_log) ----
__global__ __launch_bounds__(256) void cast_misc(
    const float* __restrict__ x, const float* __restrict__ A_log,
    _Float16* __restrict__ x_h, float* __restrict__ negA) {
  const int idx = blockIdx.x * 256 + threadIdx.x;
  const int NX = 4096 * 1024;
  if (idx < NX) {
    x_h[idx] = (_Float16)x[idx];
  } else {
    const int j = idx - NX;
    if (j < 2048 * 16) negA[j] = -__expf(A_log[j]);
  }
}

// ---- W (R x C, f32) -> Wt (C x R, f16) ----
__global__ __launch_bounds__(256) void transpose_cast(
    const float* __restrict__ in, _Float16* __restrict__ out, int R, int C) {
  __shared__ float t[32][33];
  const int bc = blockIdx.x * 32;
  const int br = blockIdx.y * 32;
  const int tx = threadIdx.x & 31;
  const int ty = threadIdx.x >> 5;  // 0..7
#pragma unroll
  for (int yy = ty; yy < 32; yy += 8)
    t[yy][tx] = in[(size_t)(br + yy) * C + bc + tx];
  __syncthreads();
#pragma unroll
  for (int yy = ty; yy < 32; yy += 8)
    out[(size_t)(bc + yy) * R + br + tx] = (_Float16)t[tx][yy];
}

// ---- causal depthwise conv(K=4) + silu over xz[:, :2048] ----
__global__ __launch_bounds__(256) void conv_silu(
    const _Float16* __restrict__ xz, const float* __restrict__ conv_w,
    const float* __restrict__ conv_b, _Float16* __restrict__ xin_h) {
  const int idx = blockIdx.x * 256 + threadIdx.x;  // over 4096*2048
  const int i = idx & 2047;
  const int ml = idx >> 11;  // b*L + l
  const int l = ml & 2047;   // position within sequence
  float a = conv_b[i];
#pragma unroll
  for (int k = 0; k < 4; ++k) {
    const int ll = l + k - 3;
    if (ll >= 0) a += conv_w[i * 4 + k] * (float)xz[(size_t)(ml + k - 3) * 4096 + i];
  }
  const float s = a / (1.f + __expf(-a));  // silu
  xin_h[idx] = (_Float16)s;
}

// ---- softplus + 16-state exp-sum + D skip + silu(z) gate ----
__global__ __launch_bounds__(256) void scan_kernel(
    const _Float16* __restrict__ dtr_h, const _Float16* __restrict__ xz,
    const _Float16* __restrict__ xin_h, const float* __restrict__ negA,
    const float* __restrict__ Dv, _Float16* __restrict__ y_h) {
  const int idx = blockIdx.x * 256 + threadIdx.x;  // over 4096*2048
  const int i = idx & 2047;
  const int ml = idx >> 11;
  const float dtr = (float)dtr_h[idx];
  // softplus, stable: max(x,0) + log1p(exp(-|x|))
  const float dt = fmaxf(dtr, 0.f) + log1pf(__expf(-fabsf(dtr)));
  const floatx4* Ap = (const floatx4*)(negA + i * 16);
  float S = 0.f;
#pragma unroll
  for (int q = 0; q < 4; ++q) {
    const floatx4 a = Ap[q];
#pragma unroll
    for (int c = 0; c < 4; ++c) S += __expf(dt * a[c]);
  }
  const float xin = (float)xin_h[idx];
  const float z = (float)xz[(size_t)ml * 4096 + 2048 + i];
  const float zs = z / (1.f + __expf(-z));
  y_h[idx] = (_Float16)(xin * (S + Dv[i]) * zs);
}

extern "C" void kernel_launch(void* const* d_in, const int* in_sizes, int n_in,
                              void* d_out, int out_size, void* d_ws,
                              size_t ws_size, hipStream_t stream) {
  const float* x = (const float*)d_in[0];
  const float* W_in = (const float*)d_in[1];
  const float* b_in = (const float*)d_in[2];
  const float* conv_w = (const float*)d_in[3];
  const float* conv_b = (const float*)d_in[4];
  const float* A_log = (const float*)d_in[5];
  const float* Dv = (const float*)d_in[6];
  const float* W_dt = (const float*)d_in[7];
  const float* b_dt = (const float*)d_in[8];
  const float* W_out = (const float*)d_in[9];
  const float* b_out = (const float*)d_in[10];
  float* out = (float*)d_out;

  char* ws = (char*)d_ws;
  size_t off = 0;
  auto alloc = [&](size_t bytes) -> void* {
    void* p = ws + off;
    off += (bytes + 255) & ~(size_t)255;
    return p;
  };
  _Float16* x_h = (_Float16*)alloc((size_t)4096 * 1024 * 2);    // 8 MB
  _Float16* Win_t = (_Float16*)alloc((size_t)4096 * 1024 * 2);  // 8 MB
  _Float16* Wdt_t = (_Float16*)alloc((size_t)2048 * 2048 * 2);  // 8 MB
  _Float16* Wout_t = (_Float16*)alloc((size_t)1024 * 2048 * 2); // 4 MB
  _Float16* xz_h = (_Float16*)alloc((size_t)4096 * 4096 * 2);   // 32 MB
  _Float16* xin_h = (_Float16*)alloc((size_t)4096 * 2048 * 2);  // 16 MB
  _Float16* dtr_h = (_Float16*)alloc((size_t)4096 * 2048 * 2);  // 16 MB
  _Float16* y_h = (_Float16*)alloc((size_t)4096 * 2048 * 2);    // 16 MB
  float* negA = (float*)alloc((size_t)2048 * 16 * 4);           // 128 KB

  // 1. casts
  cast_misc<<<(4096 * 1024 + 32768 + 255) / 256, 256, 0, stream>>>(x, A_log,
                                                                   x_h, negA);
  // 2. weight transposes (K x N -> N x K, f16)
  transpose_cast<<<dim3(4096 / 32, 1024 / 32), 256, 0, stream>>>(W_in, Win_t,
                                                                 1024, 4096);
  transpose_cast<<<dim3(2048 / 32, 2048 / 32), 256, 0, stream>>>(W_dt, Wdt_t,
                                                                 2048, 2048);
  transpose_cast<<<dim3(1024 / 32, 2048 / 32), 256, 0, stream>>>(W_out, Wout_t,
                                                                 2048, 1024);
  // 3. xz = x @ W_in + b_in
  gemm_bt<true><<<dim3(4096 / 128, 4096 / 128), 256, 0, stream>>>(
      x_h, Win_t, b_in, nullptr, xz_h, 4096, 1024);
  // 4. conv + silu
  conv_silu<<<(4096 * 2048) / 256, 256, 0, stream>>>(xz_h, conv_w, conv_b,
                                                     xin_h);
  // 5. dtraw = x_in @ W_dt + b_dt
  gemm_bt<true><<<dim3(2048 / 128, 4096 / 128), 256, 0, stream>>>(
      xin_h, Wdt_t, b_dt, nullptr, dtr_h, 2048, 2048);
  // 6. scan elementwise
  scan_kernel<<<(4096 * 2048) / 256, 256, 0, stream>>>(dtr_h, xz_h, xin_h,
                                                       negA, Dv, y_h);
  // 7. out = y @ W_out + b_out
  gemm_bt<false><<<dim3(1024 / 128, 4096 / 128), 256, 0, stream>>>(
      y_h, Wout_t, b_out, out, nullptr, 1024, 2048);
}